// Round 5
// baseline (480.022 us; speedup 1.0000x reference)
//
#include <hip/hip_runtime.h>
#include <stdint.h>

#define D_IN   2048
#define D_OUT  512

typedef __bf16 bf16;
typedef bf16     bf16x8 __attribute__((ext_vector_type(8)));
typedef float    f32x4  __attribute__((ext_vector_type(4)));
typedef uint32_t u32x4  __attribute__((ext_vector_type(4)));

#define GLP(p)  (const __attribute__((address_space(1))) void*)(p)
#define LDSP(p) (__attribute__((address_space(3))) void*)(p)

// ---------------- degree count ----------------
__global__ void k_count(const int* __restrict__ dstv, int* __restrict__ cnt, int E) {
    int e = blockIdx.x * blockDim.x + threadIdx.x;
    if (e < E) atomicAdd(&cnt[dstv[e]], 1);
}

// ---------------- hierarchical exclusive scan (+ dis, + cur=0) ----------------
__global__ __launch_bounds__(1024) void k_scan1(const int* __restrict__ cnt,
                                                int* __restrict__ offs,
                                                int* __restrict__ bsum,
                                                float* __restrict__ dis,
                                                int* __restrict__ cur, int n) {
    __shared__ int wsum[16], wbase[16];
    const int tid = threadIdx.x, lane = tid & 63, wv = tid >> 6;
    int i = blockIdx.x * 1024 + tid;
    int v = (i < n) ? cnt[i] : 0;
    int x = v;
    #pragma unroll
    for (int d = 1; d < 64; d <<= 1) {
        int y = __shfl_up(x, d);
        if (lane >= d) x += y;
    }
    if (lane == 63) wsum[wv] = x;
    __syncthreads();
    if (tid < 16) {
        int s = 0;
        for (int j = 0; j < tid; ++j) s += wsum[j];
        wbase[tid] = s;
    }
    __syncthreads();
    if (i < n) {
        offs[i] = wbase[wv] + x - v;            // block-local exclusive
        dis[i]  = rsqrtf((float)(v + 1));
        cur[i]  = 0;
    }
    if (tid == 0) bsum[blockIdx.x] = wbase[15] + wsum[15];
}

__global__ void k_scan2(int* __restrict__ bsum, int nb) {
    int t = threadIdx.x;
    if (nb <= 64) {
        int v = (t < nb) ? bsum[t] : 0;
        int x = v;
        #pragma unroll
        for (int d = 1; d < 64; d <<= 1) {
            int y = __shfl_up(x, d);
            if (t >= d) x += y;
        }
        if (t < nb) bsum[t] = x - v;   // exclusive
    } else if (t == 0) {
        int run = 0;
        for (int j = 0; j < nb; ++j) { int v = bsum[j]; bsum[j] = run; run += v; }
    }
}

// ---------------- CSR fill (offs = local + bsum) ----------------
__global__ void k_fill(const int* __restrict__ srcv, const int* __restrict__ dstv,
                       const int* __restrict__ offs, const int* __restrict__ bsum,
                       int* __restrict__ cur, int* __restrict__ csr, int E) {
    int e = blockIdx.x * blockDim.x + threadIdx.x;
    if (e < E) {
        int d = dstv[e];
        int p = offs[d] + bsum[d >> 10] + atomicAdd(&cur[d], 1);
        csr[p] = srcv[e];
    }
}

// ---------------- weight transpose + bf16 cast: wt[n][k] = (bf16)W[k][n] ----------------
__global__ void k_wt(const float* __restrict__ W, uint16_t* __restrict__ wt) {
    __shared__ float t[32][33];
    int kb = blockIdx.x * 32, nb = blockIdx.y * 32;
    int tx = threadIdx.x, ty = threadIdx.y;
    #pragma unroll
    for (int i = 0; i < 32; i += 8)
        t[ty + i][tx] = W[(size_t)(kb + ty + i) * D_OUT + nb + tx];
    __syncthreads();
    bf16* o = (bf16*)wt;
    #pragma unroll
    for (int i = 0; i < 32; i += 8)
        o[(size_t)(nb + ty + i) * D_IN + kb + tx] = (bf16)t[tx][ty + i];
}

// ---------------- fused GEMM: H[M][512] = (bf16)X[M][2048](fp32) * W ----------------
// 128x128 tile, BK=64, 4 waves (2x2), 4x4 frags of 16x16x32.
// Double-buffered LDS, ONE barrier per K-step:
//   issue {gload_lds B(t+1), ds_write A(t+1) from prefetched regs, gload A(t+2)->regs}
//   then ds_read+MFMA on buf[cur], then __syncthreads (vmcnt drain lands after MFMA phase).
// LDS tiles 128x64 bf16 (128B rows, 8x16B units), involution u^(row&7) both sides.
__global__ __launch_bounds__(256) void k_gemm(const float* __restrict__ X,
                                              const uint16_t* __restrict__ WT,
                                              uint16_t* __restrict__ H, int M) {
    __shared__ uint16_t lsA[2][128 * 64];   // 32 KB
    __shared__ uint16_t lsB[2][128 * 64];   // 32 KB
    // bijective chunked XCD swizzle: one m-panel's 4 n-blocks -> same XCD
    const int nwg = gridDim.x;
    const int b = blockIdx.x;
    const int q = nwg >> 3, r = nwg & 7;
    const int xcd = b & 7, lo = b >> 3;
    const int g = (xcd < r) ? (xcd * (q + 1) + lo) : (r * (q + 1) + (xcd - r) * q + lo);
    const int m0 = (g >> 2) * 128;
    const int n0 = (g & 3) * 128;
    const int tid = threadIdx.x;
    const int w = tid >> 6, lane = tid & 63;
    const int wr = w >> 1, wc = w & 1;
    const int lr = lane & 15, lk = lane >> 4;
    const int NT = D_IN / 64;   // 32

    f32x4 acc[4][4];
    #pragma unroll
    for (int m = 0; m < 4; m++)
        #pragma unroll
        for (int n = 0; n < 4; n++) acc[m][n] = (f32x4)(0.0f);

    // staging coords: unit uidx=(w*4+j)*64+lane; row=uidx>>3, u=uidx&7
    const float* aSrc[4];
    int aDst[4];
    const uint16_t* bSrc[4];
    #pragma unroll
    for (int j = 0; j < 4; j++) {
        int uidx = (w * 4 + j) * 64 + lane;
        int row = uidx >> 3, u = uidx & 7;
        int lrow = row;
        if (m0 + row >= M) lrow = (M - 1) - m0;   // clamp: valid data staged, stores masked
        aSrc[j] = X + (size_t)(m0 + lrow) * D_IN + u * 8;               // linear global (fp32)
        aDst[j] = row * 64 + (u ^ (row & 7)) * 8;                       // swizzled LDS (bf16 elems)
        bSrc[j] = WT + (size_t)(n0 + row) * D_IN + (u ^ (row & 7)) * 8; // pre-swizzled global
    }

    f32x4 ar0[4], ar1[4];   // A prefetch registers (one K-step: 8 floats/unit)

    auto loadA = [&](int t) {
        #pragma unroll
        for (int j = 0; j < 4; j++) {
            ar0[j] = *(const f32x4*)(aSrc[j] + t * 64);
            ar1[j] = *(const f32x4*)(aSrc[j] + t * 64 + 4);
        }
    };
    auto writeA = [&](int buf) {
        #pragma unroll
        for (int j = 0; j < 4; j++) {
            bf16x8 tv;
            tv[0] = (bf16)ar0[j][0]; tv[1] = (bf16)ar0[j][1];
            tv[2] = (bf16)ar0[j][2]; tv[3] = (bf16)ar0[j][3];
            tv[4] = (bf16)ar1[j][0]; tv[5] = (bf16)ar1[j][1];
            tv[6] = (bf16)ar1[j][2]; tv[7] = (bf16)ar1[j][3];
            *(bf16x8*)(&lsA[buf][aDst[j]]) = tv;
        }
    };
    auto stageB = [&](int t, int buf) {
        #pragma unroll
        for (int j = 0; j < 4; j++)
            __builtin_amdgcn_global_load_lds(GLP(bSrc[j] + t * 64),
                                             LDSP(&lsB[buf][(w * 4 + j) * 512]), 16, 0, 0);
    };
    auto compute = [&](int buf) {
        #pragma unroll
        for (int kk = 0; kk < 2; kk++) {
            bf16x8 aF[4], bF[4];
            #pragma unroll
            for (int m = 0; m < 4; m++) {
                int row = wr * 64 + m * 16 + lr;
                aF[m] = *(const bf16x8*)(&lsA[buf][row * 64 + (((kk * 4 + lk) ^ (row & 7)) * 8)]);
            }
            #pragma unroll
            for (int n = 0; n < 4; n++) {
                int row = wc * 64 + n * 16 + lr;
                bF[n] = *(const bf16x8*)(&lsB[buf][row * 64 + (((kk * 4 + lk) ^ (row & 7)) * 8)]);
            }
            #pragma unroll
            for (int m = 0; m < 4; m++)
                #pragma unroll
                for (int n = 0; n < 4; n++)
                    acc[m][n] = __builtin_amdgcn_mfma_f32_16x16x32_bf16(aF[m], bF[n], acc[m][n], 0, 0, 0);
        }
    };
    auto body = [&](int t, int bufc) {
        int bufn = bufc ^ 1;
        if (t + 1 < NT) {
            stageB(t + 1, bufn);                 // async -> LDS, drained at this body's barrier
            writeA(bufn);                        // A(t+1) from regs prefetched at body(t-1)
            loadA(t + 2 < NT ? t + 2 : t);       // prefetch A(t+2); clamped dummy at tail
        }
        compute(bufc);
        __syncthreads();                          // vmcnt+lgkm drain after full MFMA phase
    };

    // prologue: fill buf0, prefetch A(1)
    loadA(0);
    stageB(0, 0);
    writeA(0);
    loadA(1);
    __syncthreads();

    for (int t = 0; t < NT; t += 2) {            // unrolled x2: static buffer indices
        body(t, 0);
        body(t + 1, 1);
    }

    // epilogue: C/D layout col=lane&15, row=(lane>>4)*4+reg; store bf16
    #pragma unroll
    for (int m = 0; m < 4; m++) {
        int rbase = m0 + wr * 64 + m * 16 + lk * 4;
        #pragma unroll
        for (int n = 0; n < 4; n++) {
            int col = n0 + wc * 64 + n * 16 + lr;
            #pragma unroll
            for (int j = 0; j < 4; j++) {
                int row = rbase + j;
                if (row < M) {
                    bf16 t = (bf16)acc[m][n][j];
                    H[(size_t)row * D_OUT + col] = __builtin_bit_cast(uint16_t, t);
                }
            }
        }
    }
}

// ---------------- aggregation + bias + log_softmax, one wave per node ----------------
__global__ __launch_bounds__(256) void k_agg(const uint16_t* __restrict__ h,
                                             const int* __restrict__ csr,
                                             const int* __restrict__ offs,
                                             const int* __restrict__ bsum,
                                             const int* __restrict__ cnt,
                                             const float* __restrict__ dis,
                                             const float* __restrict__ bias,
                                             float* __restrict__ out, int N) {
    const int wv = threadIdx.x >> 6, lane = threadIdx.x & 63;
    const int i = blockIdx.x * 4 + wv;
    if (i >= N) return;
    const float di = dis[i];
    float acc[8];
    {
        u32x4 v = *(const u32x4*)(h + (size_t)i * D_OUT + lane * 8);
        float s2 = di * di;
        #pragma unroll
        for (int k = 0; k < 4; k++) {
            acc[2 * k]     = __builtin_bit_cast(float, v[k] << 16) * s2;
            acc[2 * k + 1] = __builtin_bit_cast(float, v[k] & 0xffff0000u) * s2;
        }
    }
    const int o = offs[i] + bsum[i >> 10], c = cnt[i];
    for (int e = o; e < o + c; ++e) {
        int s = csr[e];
        float ws = di * dis[s];
        u32x4 v = *(const u32x4*)(h + (size_t)s * D_OUT + lane * 8);
        #pragma unroll
        for (int k = 0; k < 4; k++) {
            acc[2 * k]     += __builtin_bit_cast(float, v[k] << 16) * ws;
            acc[2 * k + 1] += __builtin_bit_cast(float, v[k] & 0xffff0000u) * ws;
        }
    }
    {
        const f32x4* bp = (const f32x4*)(bias + lane * 8);
        f32x4 b0 = bp[0], b1 = bp[1];
        #pragma unroll
        for (int k = 0; k < 4; k++) { acc[k] += b0[k]; acc[4 + k] += b1[k]; }
    }
    float mx = acc[0];
    #pragma unroll
    for (int k = 1; k < 8; k++) mx = fmaxf(mx, acc[k]);
    #pragma unroll
    for (int d = 1; d < 64; d <<= 1) mx = fmaxf(mx, __shfl_xor(mx, d));
    float se = 0.f;
    #pragma unroll
    for (int k = 0; k < 8; k++) se += expf(acc[k] - mx);
    #pragma unroll
    for (int d = 1; d < 64; d <<= 1) se += __shfl_xor(se, d);
    float lse = mx + logf(se);
    f32x4 o0, o1;
    #pragma unroll
    for (int k = 0; k < 4; k++) { o0[k] = acc[k] - lse; o1[k] = acc[4 + k] - lse; }
    f32x4* op = (f32x4*)(out + (size_t)i * D_OUT + lane * 8);
    op[0] = o0; op[1] = o1;
}

// ---------------- launch ----------------
extern "C" void kernel_launch(void* const* d_in, const int* in_sizes, int n_in,
                              void* d_out, int out_size, void* d_ws, size_t ws_size,
                              hipStream_t stream) {
    const float* x    = (const float*)d_in[0];
    const int*   ei   = (const int*)d_in[1];
    const float* W    = (const float*)d_in[2];
    const float* bias = (const float*)d_in[3];
    float* out = (float*)d_out;

    const int N = in_sizes[0] / D_IN;     // 50000
    const int E = in_sizes[1] / 2;        // 400000
    const int* srcv = ei;
    const int* dstv = ei + E;

    char* p = (char*)d_ws;
    auto carve = [&](size_t b) { void* r = (void*)p; p += (b + 255) & ~(size_t)255; return r; };
    uint16_t* h    = (uint16_t*)carve((size_t)N * D_OUT * 2);            // 51.2 MB
    uint16_t* wt   = (uint16_t*)carve((size_t)D_OUT * D_IN * 2);         // 2 MB
    int*      cnt  = (int*)carve((size_t)N * 4);
    int*      cur  = (int*)carve((size_t)N * 4);
    float*    dis  = (float*)carve((size_t)N * 4);
    int*      offs = (int*)carve((size_t)N * 4);
    int*      csr  = (int*)carve((size_t)E * 4);
    int*      bsum = (int*)carve(1024 * 4);

    hipMemsetAsync(cnt, 0, (size_t)N * 4, stream);

    k_wt<<<dim3(D_IN / 32, D_OUT / 32), dim3(32, 8), 0, stream>>>(W, wt);
    k_count<<<(E + 255) / 256, 256, 0, stream>>>(dstv, cnt, E);
    const int nb = (N + 1023) / 1024;
    k_scan1<<<nb, 1024, 0, stream>>>(cnt, offs, bsum, dis, cur, N);
    k_scan2<<<1, 64, 0, stream>>>(bsum, nb);
    k_fill<<<(E + 255) / 256, 256, 0, stream>>>(srcv, dstv, offs, bsum, cur, csr, E);

    k_gemm<<<((N + 127) / 128) * 4, 256, 0, stream>>>(x, wt, h, N);

    k_agg<<<(N + 3) / 4, 256, 0, stream>>>(h, csr, offs, bsum, cnt, dis, bias, out, N);
}

// Round 6
// 358.882 us; speedup vs baseline: 1.3375x; 1.3375x over previous
//
#include <hip/hip_runtime.h>
#include <stdint.h>

#define D_IN   2048
#define D_OUT  512

typedef __bf16 bf16;
typedef bf16     bf16x8 __attribute__((ext_vector_type(8)));
typedef float    f32x4  __attribute__((ext_vector_type(4)));
typedef uint32_t u32x4  __attribute__((ext_vector_type(4)));

#define GLP(p)  (const __attribute__((address_space(1))) void*)(p)
#define LDSP(p) (__attribute__((address_space(3))) void*)(p)

// ---------------- degree count ----------------
__global__ void k_count(const int* __restrict__ dstv, int* __restrict__ cnt, int E) {
    int e = blockIdx.x * blockDim.x + threadIdx.x;
    if (e < E) atomicAdd(&cnt[dstv[e]], 1);
}

// ---------------- hierarchical exclusive scan (+ dis, + cur=0) ----------------
__global__ __launch_bounds__(1024) void k_scan1(const int* __restrict__ cnt,
                                                int* __restrict__ offs,
                                                int* __restrict__ bsum,
                                                float* __restrict__ dis,
                                                int* __restrict__ cur, int n) {
    __shared__ int wsum[16], wbase[16];
    const int tid = threadIdx.x, lane = tid & 63, wv = tid >> 6;
    int i = blockIdx.x * 1024 + tid;
    int v = (i < n) ? cnt[i] : 0;
    int x = v;
    #pragma unroll
    for (int d = 1; d < 64; d <<= 1) {
        int y = __shfl_up(x, d);
        if (lane >= d) x += y;
    }
    if (lane == 63) wsum[wv] = x;
    __syncthreads();
    if (tid < 16) {
        int s = 0;
        for (int j = 0; j < tid; ++j) s += wsum[j];
        wbase[tid] = s;
    }
    __syncthreads();
    if (i < n) {
        offs[i] = wbase[wv] + x - v;            // block-local exclusive
        dis[i]  = rsqrtf((float)(v + 1));
        cur[i]  = 0;
    }
    if (tid == 0) bsum[blockIdx.x] = wbase[15] + wsum[15];
}

__global__ void k_scan2(int* __restrict__ bsum, int nb) {
    int t = threadIdx.x;
    if (nb <= 64) {
        int v = (t < nb) ? bsum[t] : 0;
        int x = v;
        #pragma unroll
        for (int d = 1; d < 64; d <<= 1) {
            int y = __shfl_up(x, d);
            if (t >= d) x += y;
        }
        if (t < nb) bsum[t] = x - v;   // exclusive
    } else if (t == 0) {
        int run = 0;
        for (int j = 0; j < nb; ++j) { int v = bsum[j]; bsum[j] = run; run += v; }
    }
}

// ---------------- CSR fill (offs = local + bsum) ----------------
__global__ void k_fill(const int* __restrict__ srcv, const int* __restrict__ dstv,
                       const int* __restrict__ offs, const int* __restrict__ bsum,
                       int* __restrict__ cur, int* __restrict__ csr, int E) {
    int e = blockIdx.x * blockDim.x + threadIdx.x;
    if (e < E) {
        int d = dstv[e];
        int p = offs[d] + bsum[d >> 10] + atomicAdd(&cur[d], 1);
        csr[p] = srcv[e];
    }
}

// ---------------- weight transpose + bf16 cast: wt[n][k] = (bf16)W[k][n] ----------------
__global__ void k_wt(const float* __restrict__ W, uint16_t* __restrict__ wt) {
    __shared__ float t[32][33];
    int kb = blockIdx.x * 32, nb = blockIdx.y * 32;
    int tx = threadIdx.x, ty = threadIdx.y;
    #pragma unroll
    for (int i = 0; i < 32; i += 8)
        t[ty + i][tx] = W[(size_t)(kb + ty + i) * D_OUT + nb + tx];
    __syncthreads();
    bf16* o = (bf16*)wt;
    #pragma unroll
    for (int i = 0; i < 32; i += 8)
        o[(size_t)(nb + ty + i) * D_IN + kb + tx] = (bf16)t[tx][ty + i];
}

// ---------------- fused GEMM: H[M][512] = (bf16)X[M][2048](fp32) * W ----------------
// 128x128 tile, BK=64, 4 waves (2x2), 4x4 frags of 16x16x32.
// T3/T4 pipeline: double-buffered LDS, COUNTED vmcnt(12) + RAW s_barrier
// (no vmcnt(0) drain in the loop) — next tile's 12 loads stay in flight
// across the barrier. Queue invariant at iter entry: [B(t)x4, A(t+1)x8].
// LDS tiles 128x64 bf16 (128B rows, 8x16B units), involution u^(row&7).
__global__ __launch_bounds__(256, 2) void k_gemm(const float* __restrict__ X,
                                                 const uint16_t* __restrict__ WT,
                                                 uint16_t* __restrict__ H, int M) {
    __shared__ uint16_t lsA[2][128 * 64];   // 32 KB
    __shared__ uint16_t lsB[2][128 * 64];   // 32 KB
    // bijective chunked XCD swizzle: one m-panel's 4 n-blocks -> same XCD
    const int nwg = gridDim.x;
    const int b = blockIdx.x;
    const int q = nwg >> 3, r = nwg & 7;
    const int xcd = b & 7, lo = b >> 3;
    const int g = (xcd < r) ? (xcd * (q + 1) + lo) : (r * (q + 1) + (xcd - r) * q + lo);
    const int m0 = (g >> 2) * 128;
    const int n0 = (g & 3) * 128;
    const int tid = threadIdx.x;
    const int w = tid >> 6, lane = tid & 63;
    const int wr = w >> 1, wc = w & 1;
    const int lr = lane & 15, lk = lane >> 4;
    const int NT = D_IN / 64;   // 32

    f32x4 acc[4][4];
    #pragma unroll
    for (int m = 0; m < 4; m++)
        #pragma unroll
        for (int n = 0; n < 4; n++) acc[m][n] = (f32x4)(0.0f);

    // staging coords: unit uidx=(w*4+j)*64+lane; row=uidx>>3, u=uidx&7
    const float* aSrc[4];
    int aDst[4];
    const uint16_t* bSrc[4];
    #pragma unroll
    for (int j = 0; j < 4; j++) {
        int uidx = (w * 4 + j) * 64 + lane;
        int row = uidx >> 3, u = uidx & 7;
        int lrow = row;
        if (m0 + row >= M) lrow = (M - 1) - m0;   // clamp: valid data staged, stores masked
        aSrc[j] = X + (size_t)(m0 + lrow) * D_IN + u * 8;               // linear global (fp32)
        aDst[j] = row * 64 + (u ^ (row & 7)) * 8;                       // swizzled LDS (bf16 elems)
        bSrc[j] = WT + (size_t)(n0 + row) * D_IN + (u ^ (row & 7)) * 8; // pre-swizzled global
    }

    f32x4 set0[8], set1[8];   // two A-prefetch register sets (8 f32x4 each)

    auto loadA = [&](f32x4* s, int t) {
        t &= (NT - 1);                           // wrap: tail iterations stage dummies
        #pragma unroll
        for (int j = 0; j < 4; j++) {
            s[2 * j]     = *(const f32x4*)(aSrc[j] + t * 64);
            s[2 * j + 1] = *(const f32x4*)(aSrc[j] + t * 64 + 4);
        }
    };
    auto writeA = [&](const f32x4* s, int buf) {
        #pragma unroll
        for (int j = 0; j < 4; j++) {
            f32x4 a0 = s[2 * j], a1 = s[2 * j + 1];
            bf16x8 tv;
            tv[0] = (bf16)a0[0]; tv[1] = (bf16)a0[1]; tv[2] = (bf16)a0[2]; tv[3] = (bf16)a0[3];
            tv[4] = (bf16)a1[0]; tv[5] = (bf16)a1[1]; tv[6] = (bf16)a1[2]; tv[7] = (bf16)a1[3];
            *(bf16x8*)(&lsA[buf][aDst[j]]) = tv;
        }
    };
    auto stageB = [&](int t, int buf) {
        t &= (NT - 1);
        #pragma unroll
        for (int j = 0; j < 4; j++)
            __builtin_amdgcn_global_load_lds(GLP(bSrc[j] + t * 64),
                                             LDSP(&lsB[buf][(w * 4 + j) * 512]), 16, 0, 0);
    };
    auto compute = [&](int buf) {
        #pragma unroll
        for (int kk = 0; kk < 2; kk++) {
            bf16x8 aF[4], bF[4];
            #pragma unroll
            for (int m = 0; m < 4; m++) {
                int row = wr * 64 + m * 16 + lr;
                aF[m] = *(const bf16x8*)(&lsA[buf][row * 64 + (((kk * 4 + lk) ^ (row & 7)) * 8)]);
            }
            #pragma unroll
            for (int n = 0; n < 4; n++) {
                int row = wc * 64 + n * 16 + lr;
                bF[n] = *(const bf16x8*)(&lsB[buf][row * 64 + (((kk * 4 + lk) ^ (row & 7)) * 8)]);
            }
            #pragma unroll
            for (int m = 0; m < 4; m++)
                #pragma unroll
                for (int n = 0; n < 4; n++)
                    acc[m][n] = __builtin_amdgcn_mfma_f32_16x16x32_bf16(aF[m], bF[n], acc[m][n], 0, 0, 0);
        }
    };

    // prologue: establish invariant (queue = [B(0)x4, A(1)x8]; lsA[0] holds tile 0)
    loadA(set0, 0);                                        // 8 in flight
    stageB(0, 0);                                          // +4
    loadA(set1, 1);                                        // +8 = 20
    asm volatile("s_waitcnt vmcnt(12)" ::: "memory");      // A(0) done (B0+A1 remain)
    writeA(set0, 0);                                       // tile 0 -> lsA[0]

    #pragma unroll 1
    for (int t = 0; t < NT; t += 2) {
        // even iter: compute buf 0
        stageB(t + 1, 1);                                  // queue: B(t),A(t+1),B(t+1)
        loadA(set0, t + 2);                                // +A(t+2) = 24
        asm volatile("s_waitcnt vmcnt(12)" ::: "memory");  // B(t), A(t+1) done
        writeA(set1, 1);                                   // tile t+1 -> lsA[1]
        asm volatile("s_waitcnt lgkmcnt(0)" ::: "memory"); // own ds_writes landed
        __builtin_amdgcn_s_barrier();                      // tile t fully published
        compute(0);
        __builtin_amdgcn_s_barrier();                      // all reads of buf0 done
        // odd iter: compute buf 1
        stageB(t + 2, 0);
        loadA(set1, t + 3);
        asm volatile("s_waitcnt vmcnt(12)" ::: "memory");  // B(t+1), A(t+2) done
        writeA(set0, 0);                                   // tile t+2 -> lsA[0]
        asm volatile("s_waitcnt lgkmcnt(0)" ::: "memory");
        __builtin_amdgcn_s_barrier();
        compute(1);
        __builtin_amdgcn_s_barrier();
    }
    asm volatile("s_waitcnt vmcnt(0)" ::: "memory");       // drain dummy DMAs before exit

    // epilogue: C/D layout col=lane&15, row=(lane>>4)*4+reg; store bf16
    #pragma unroll
    for (int m = 0; m < 4; m++) {
        int rbase = m0 + wr * 64 + m * 16 + lk * 4;
        #pragma unroll
        for (int n = 0; n < 4; n++) {
            int col = n0 + wc * 64 + n * 16 + lr;
            #pragma unroll
            for (int j = 0; j < 4; j++) {
                int row = rbase + j;
                if (row < M) {
                    bf16 tv = (bf16)acc[m][n][j];
                    H[(size_t)row * D_OUT + col] = __builtin_bit_cast(uint16_t, tv);
                }
            }
        }
    }
}

// ---------------- aggregation + bias + log_softmax, one wave per node ----------------
__global__ __launch_bounds__(256) void k_agg(const uint16_t* __restrict__ h,
                                             const int* __restrict__ csr,
                                             const int* __restrict__ offs,
                                             const int* __restrict__ bsum,
                                             const int* __restrict__ cnt,
                                             const float* __restrict__ dis,
                                             const float* __restrict__ bias,
                                             float* __restrict__ out, int N) {
    const int wv = threadIdx.x >> 6, lane = threadIdx.x & 63;
    const int i = blockIdx.x * 4 + wv;
    if (i >= N) return;
    const float di = dis[i];
    float acc[8];
    {
        u32x4 v = *(const u32x4*)(h + (size_t)i * D_OUT + lane * 8);
        float s2 = di * di;
        #pragma unroll
        for (int k = 0; k < 4; k++) {
            acc[2 * k]     = __builtin_bit_cast(float, v[k] << 16) * s2;
            acc[2 * k + 1] = __builtin_bit_cast(float, v[k] & 0xffff0000u) * s2;
        }
    }
    const int o = offs[i] + bsum[i >> 10], c = cnt[i];
    for (int e = o; e < o + c; ++e) {
        int s = csr[e];
        float ws = di * dis[s];
        u32x4 v = *(const u32x4*)(h + (size_t)s * D_OUT + lane * 8);
        #pragma unroll
        for (int k = 0; k < 4; k++) {
            acc[2 * k]     += __builtin_bit_cast(float, v[k] << 16) * ws;
            acc[2 * k + 1] += __builtin_bit_cast(float, v[k] & 0xffff0000u) * ws;
        }
    }
    {
        const f32x4* bp = (const f32x4*)(bias + lane * 8);
        f32x4 b0 = bp[0], b1 = bp[1];
        #pragma unroll
        for (int k = 0; k < 4; k++) { acc[k] += b0[k]; acc[4 + k] += b1[k]; }
    }
    float mx = acc[0];
    #pragma unroll
    for (int k = 1; k < 8; k++) mx = fmaxf(mx, acc[k]);
    #pragma unroll
    for (int d = 1; d < 64; d <<= 1) mx = fmaxf(mx, __shfl_xor(mx, d));
    float se = 0.f;
    #pragma unroll
    for (int k = 0; k < 8; k++) se += expf(acc[k] - mx);
    #pragma unroll
    for (int d = 1; d < 64; d <<= 1) se += __shfl_xor(se, d);
    float lse = mx + logf(se);
    f32x4 o0, o1;
    #pragma unroll
    for (int k = 0; k < 4; k++) { o0[k] = acc[k] - lse; o1[k] = acc[4 + k] - lse; }
    f32x4* op = (f32x4*)(out + (size_t)i * D_OUT + lane * 8);
    op[0] = o0; op[1] = o1;
}

// ---------------- launch ----------------
extern "C" void kernel_launch(void* const* d_in, const int* in_sizes, int n_in,
                              void* d_out, int out_size, void* d_ws, size_t ws_size,
                              hipStream_t stream) {
    const float* x    = (const float*)d_in[0];
    const int*   ei   = (const int*)d_in[1];
    const float* W    = (const float*)d_in[2];
    const float* bias = (const float*)d_in[3];
    float* out = (float*)d_out;

    const int N = in_sizes[0] / D_IN;     // 50000
    const int E = in_sizes[1] / 2;        // 400000
    const int* srcv = ei;
    const int* dstv = ei + E;

    char* p = (char*)d_ws;
    auto carve = [&](size_t b) { void* r = (void*)p; p += (b + 255) & ~(size_t)255; return r; };
    uint16_t* h    = (uint16_t*)carve((size_t)N * D_OUT * 2);            // 51.2 MB
    uint16_t* wt   = (uint16_t*)carve((size_t)D_OUT * D_IN * 2);         // 2 MB
    int*      cnt  = (int*)carve((size_t)N * 4);
    int*      cur  = (int*)carve((size_t)N * 4);
    float*    dis  = (float*)carve((size_t)N * 4);
    int*      offs = (int*)carve((size_t)N * 4);
    int*      csr  = (int*)carve((size_t)E * 4);
    int*      bsum = (int*)carve(1024 * 4);

    hipMemsetAsync(cnt, 0, (size_t)N * 4, stream);

    k_wt<<<dim3(D_IN / 32, D_OUT / 32), dim3(32, 8), 0, stream>>>(W, wt);
    k_count<<<(E + 255) / 256, 256, 0, stream>>>(dstv, cnt, E);
    const int nb = (N + 1023) / 1024;
    k_scan1<<<nb, 1024, 0, stream>>>(cnt, offs, bsum, dis, cur, N);
    k_scan2<<<1, 64, 0, stream>>>(bsum, nb);
    k_fill<<<(E + 255) / 256, 256, 0, stream>>>(srcv, dstv, offs, bsum, cur, csr, E);

    k_gemm<<<((N + 127) / 128) * 4, 256, 0, stream>>>(x, wt, h, N);

    k_agg<<<(N + 3) / 4, 256, 0, stream>>>(h, csr, offs, bsum, cnt, dis, bias, out, N);
}